// Round 15
// baseline (189.447 us; speedup 1.0000x reference)
//
#include <hip/hip_runtime.h>
#include <hip/hip_bf16.h>

#define N_NODES 4096
#define E_EDGES 131072
#define DIN_    512
#define DM_     256
#define DFF_    2048
#define EPS_    1e-5f
#define NSPLIT  8

typedef __attribute__((ext_vector_type(8))) short bf16x8;   // 8 bf16 = 4 VGPR
typedef __attribute__((ext_vector_type(4))) float f32x4;

__device__ __forceinline__ short f2b(float f) {
    union { float f; unsigned u; } x; x.f = f;
    unsigned r = x.u + 0x7fff + ((x.u >> 16) & 1);   // RNE
    return (short)(r >> 16);
}

// async global->LDS, 16B per lane; lptr must be wave-uniform (HW adds lane*16)
__device__ __forceinline__ void gload16(const void* g, void* l) {
    __builtin_amdgcn_global_load_lds(
        (const __attribute__((address_space(1))) void*)g,
        (__attribute__((address_space(3))) void*)l, 16, 0, 0);
}

// ---------------------------------------------------------------------------
// merged f32->bf16 casts + W_gcn transpose, one launch.
// ---------------------------------------------------------------------------
__global__ __launch_bounds__(256)
void castall_kernel(const float* __restrict__ x, short* __restrict__ xb,
                    const float* __restrict__ inw, short* __restrict__ inwb,
                    const float* __restrict__ ow, short* __restrict__ owb,
                    const float* __restrict__ l1w, short* __restrict__ l1wb,
                    const float* __restrict__ l2w, short* __restrict__ l2wb,
                    const float* __restrict__ Wg, short* __restrict__ WgT) {
    const int b = blockIdx.x;
    __shared__ float t[32][33];
    if (b >= 3328) {                       // W_gcn [512][256] -> WgT [256][512]
        const int b2 = b - 3328;
        const int bk = (b2 & 15) * 32, bn = (b2 >> 4) * 32;
        const int tx = threadIdx.x & 31, ty = threadIdx.x >> 5;
        #pragma unroll
        for (int i = 0; i < 4; ++i) {
            int r = ty + i * 8;
            t[r][tx] = Wg[(size_t)(bk + r) * DM_ + bn + tx];
        }
        __syncthreads();
        #pragma unroll
        for (int i = 0; i < 4; ++i) {
            int r = ty + i * 8;
            WgT[(size_t)(bn + r) * DIN_ + bk + tx] = f2b(t[tx][r]);
        }
        return;
    }
    const float* s; short* d; int base;
    if (b < 2048)      { s = x;   d = xb;   base = b * 256; }
    else if (b < 2240) { s = inw; d = inwb; base = (b - 2048) * 256; }
    else if (b < 2304) { s = ow;  d = owb;  base = (b - 2240) * 256; }
    else if (b < 2816) { s = l1w; d = l1wb; base = (b - 2304) * 256; }
    else               { s = l2w; d = l2wb; base = (b - 2816) * 256; }
    const int i = base + threadIdx.x;
    float4 v = reinterpret_cast<const float4*>(s)[i];
    union { short s[4]; int2 v; } o;
    o.s[0] = f2b(v.x); o.s[1] = f2b(v.y); o.s[2] = f2b(v.z); o.s[3] = f2b(v.w);
    reinterpret_cast<int2*>(d)[i] = o.v;
}

// xw f32 [4096][256] -> xwb bf16 (gather reads 34x on avg; halves that traffic)
__global__ __launch_bounds__(256)
void castxw_kernel(const float* __restrict__ s, short* __restrict__ d) {
    const int i = blockIdx.x * 256 + threadIdx.x;
    float4 v = reinterpret_cast<const float4*>(s)[i];
    union { short s[4]; int2 v; } o;
    o.s[0] = f2b(v.x); o.s[1] = f2b(v.y); o.s[2] = f2b(v.z); o.s[3] = f2b(v.w);
    reinterpret_cast<int2*>(d)[i] = o.v;
}

// ---------------------------------------------------------------------------
// bf16 MFMA GEMM, 2-phase double-buffered, M-tile templated (MT = 128 or 64).
// ---------------------------------------------------------------------------
template<int MT, bool BF16OUT, bool RELU, bool SPLITK>
__global__ __launch_bounds__(256)
void mgemm_kernel(const short* __restrict__ A, const short* __restrict__ B,
                  const float* __restrict__ bias,
                  float* __restrict__ Cf, short* __restrict__ Cb,
                  short* __restrict__ VTout,
                  int M, int N, int K, int lda, int ldb, int ldc, int kchunk)
{
    constexpr int MFN = MT / 32;                   // mf fragments per wave
    constexpr int ACH = MT / 64;                   // A-stage chunks per thread
    __shared__ __align__(16) short As[2][MT * 32];
    __shared__ __align__(16) short Bs[2][128 * 32];
    const int tid = threadIdx.x;
    const int lane = tid & 63, w = tid >> 6;
    const int c = lane & 15, g = lane >> 4;
    const int wm = (w >> 1) * (MT / 2), wn = (w & 1) * 64;
    const int bm = blockIdx.y * MT, bn = blockIdx.x * 128;
    int k0 = 0, kend = K;
    if (SPLITK) { k0 = blockIdx.z * kchunk; kend = min(K, k0 + kchunk); }

    const int wbase = (tid & ~63) * 16;            // wave-uniform LDS byte base
    int srowA[ACH], soffA[ACH];
    #pragma unroll
    for (int i = 0; i < ACH; ++i) {
        int L = i * 256 + tid;
        srowA[i] = L >> 2;
        soffA[i] = ((L & 3) ^ ((srowA[i] >> 1) & 3)) * 8;   // shorts
    }
    int srowB[2], soffB[2];
    #pragma unroll
    for (int i = 0; i < 2; ++i) {
        int L = i * 256 + tid;
        srowB[i] = L >> 2;
        soffB[i] = ((L & 3) ^ ((srowB[i] >> 1) & 3)) * 8;
    }

    auto stage = [&](int b, int kb) {
        #pragma unroll
        for (int i = 0; i < ACH; ++i)
            gload16(A + (size_t)(bm + srowA[i]) * lda + kb + soffA[i],
                    (char*)As[b] + i * 4096 + wbase);
        #pragma unroll
        for (int i = 0; i < 2; ++i)
            gload16(B + (size_t)(bn + srowB[i]) * ldb + kb + soffB[i],
                    (char*)Bs[b] + i * 4096 + wbase);
    };

    const int nsteps = (kend - k0) >> 5;
    f32x4 acc[MFN][4] = {};
    stage(0, k0);
    for (int s = 0; s < nsteps; ++s) {
        const int cur = s & 1;
        const bool pf = (s + 1 < nsteps);
        if (pf) stage(cur ^ 1, k0 + (s + 1) * 32);    // WAR-safe: drained at s-1 bar2
        if (pf) {
            if constexpr (ACH == 2) asm volatile("s_waitcnt vmcnt(4)" ::: "memory");
            else                    asm volatile("s_waitcnt vmcnt(3)" ::: "memory");
        } else {
            asm volatile("s_waitcnt vmcnt(0)" ::: "memory");
        }
        __builtin_amdgcn_s_barrier();                 // all waves' cur landed
        bf16x8 af[MFN], bf[4];
        #pragma unroll
        for (int mf = 0; mf < MFN; ++mf) {
            int r = wm + mf * 16 + c;
            int sw = (g ^ ((r >> 1) & 3)) * 16;
            af[mf] = *reinterpret_cast<const bf16x8*>((const char*)As[cur] + r * 64 + sw);
        }
        #pragma unroll
        for (int nf = 0; nf < 4; ++nf) {
            int r = wn + nf * 16 + c;
            int sw = (g ^ ((r >> 1) & 3)) * 16;
            bf[nf] = *reinterpret_cast<const bf16x8*>((const char*)Bs[cur] + r * 64 + sw);
        }
        #pragma unroll
        for (int mf = 0; mf < MFN; ++mf)
            #pragma unroll
            for (int nf = 0; nf < 4; ++nf)
                acc[mf][nf] = __builtin_amdgcn_mfma_f32_16x16x32_bf16(
                    af[mf], bf[nf], acc[mf][nf], 0, 0, 0);
        __builtin_amdgcn_s_barrier();                 // all reads of cur done
    }
    #pragma unroll
    for (int mf = 0; mf < MFN; ++mf) {
        const int row = bm + wm + mf * 16 + g * 4;
        #pragma unroll
        for (int nf = 0; nf < 4; ++nf) {
            const int col = bn + wn + nf * 16 + c;
            float bv = bias ? bias[col] : 0.f;
            #pragma unroll
            for (int v = 0; v < 4; ++v) {
                float val = acc[mf][nf][v];
                size_t o = (size_t)(row + v) * ldc + col;
                if (SPLITK) {
                    if (blockIdx.z == 0) val += bv;
                    atomicAdd(&Cf[o], val);
                } else {
                    val += bv;
                    if (RELU) val = fmaxf(val, 0.f);
                    if (BF16OUT) {
                        short bvs = f2b(val);
                        Cb[o] = bvs;
                        if (VTout && col >= 512)
                            VTout[(size_t)(col - 512) * N_NODES + row + v] = bvs;
                    } else {
                        Cf[o] = val;
                    }
                }
            }
        }
    }
}

// ---------------------------------------------------------------------------
// Flash attention (unchanged from round 14 -- control).
// ---------------------------------------------------------------------------
__global__ __launch_bounds__(256)
void fattn_kernel(const short* __restrict__ qkv, const short* __restrict__ VT,
                  short* __restrict__ Opart, float* __restrict__ ml)
{
    const int bid = blockIdx.x;
    const int j = bid >> 3;
    const int pair = 2 * (bid & 7) + (j & 1);
    const int hd = pair >> 3, sp = pair & 7;
    const int qt = j >> 1;
    const int tid = threadIdx.x;
    const int w = tid >> 6, lane = tid & 63;
    const int c = lane & 15, g = lane >> 4;
    const int q0 = qt * 64 + w * 16;

    __shared__ __align__(16) char smem[40960];   // K 16K | V 16K | P 4x2048
    char* KldsB = smem;
    char* VldsB = smem + 16384;
    char* Pbase = smem + 32768 + w * 2048;       // [16][64] XOR-swizzled

    const char* qkvC = (const char*)qkv;
    const char* vtC  = (const char*)VT;
    const int wbase = (tid & ~63) * 16;          // wave-uniform LDS chunk base

    const short* Q = qkv + (size_t)q0 * 768 + hd * 128;
    bf16x8 qf[4];
    #pragma unroll
    for (int ks = 0; ks < 4; ++ks)
        qf[ks] = *reinterpret_cast<const bf16x8*>(Q + (size_t)c * 768 + ks * 32 + g * 8);

    auto stageK = [&](int kt) {
        const int key0 = kt * 64;
        #pragma unroll
        for (int i = 0; i < 4; ++i) {
            int Lr  = i * 4096 + tid * 16;
            int key = Lr >> 8;
            int lg  = (Lr & 255) ^ ((key & 7) << 4);
            const char* src = qkvC + ((size_t)(key0 + key) * 768 + 256 + hd * 128) * 2 + lg;
            gload16(src, KldsB + i * 4096 + wbase);
        }
    };
    auto stageV = [&](int kt) {
        const int key0 = kt * 64;
        #pragma unroll
        for (int i = 0; i < 4; ++i) {
            int Lr = i * 4096 + tid * 16;
            int dh = Lr >> 7;
            int lg = (Lr & 127) ^ ((dh & 7) << 4);
            const char* src = vtC + (size_t)(hd * 128 + dh) * 8192 + key0 * 2 + lg;
            gload16(src, VldsB + i * 4096 + wbase);
        }
    };

    f32x4 O[8] = {};
    float m[4]  = {-1e30f, -1e30f, -1e30f, -1e30f};
    float lsum[4] = {};                       // per-lane partial row sums
    const float C = 0.12751744f;              // log2(e)/sqrt(128)

    stageK(sp * 8);
    stageV(sp * 8);

    for (int t = 0; t < 8; ++t) {
        asm volatile("s_waitcnt vmcnt(4)" ::: "memory");
        __builtin_amdgcn_s_barrier();         // all waves' K(t) visible
        // ---- QK^T from LDS ----
        f32x4 S[4] = {};
        #pragma unroll
        for (int nf = 0; nf < 4; ++nf) {
            const int key = nf * 16 + c;
            const char* kr = KldsB + key * 256;
            const int sw = (key & 7) << 4;
            #pragma unroll
            for (int ks = 0; ks < 4; ++ks) {
                bf16x8 kf = *reinterpret_cast<const bf16x8*>(kr + ((ks * 64 + g * 16) ^ sw));
                S[nf] = __builtin_amdgcn_mfma_f32_16x16x32_bf16(qf[ks], kf, S[nf], 0, 0, 0);
            }
        }
        __builtin_amdgcn_s_barrier();         // all QK reads done -> K free
        if (t < 7) stageK(sp * 8 + t + 1);    // hides under softmax+PV

        // ---- online softmax, defer-max (log2 units, per-lane lsum) ----
        float z[4][4];
        float lmax[4];
        bool ok = true;
        #pragma unroll
        for (int v = 0; v < 4; ++v) {
            #pragma unroll
            for (int nf = 0; nf < 4; ++nf) z[nf][v] = S[nf][v] * C;
            lmax[v] = fmaxf(fmaxf(z[0][v], z[1][v]), fmaxf(z[2][v], z[3][v]));
            ok = ok && (lmax[v] <= m[v] + 8.f);
        }
        if (!__all(ok)) {                     // rare after tile 0
            float mx[4];
            #pragma unroll
            for (int v = 0; v < 4; ++v) mx[v] = lmax[v];
            #pragma unroll
            for (int off = 1; off <= 8; off <<= 1)
                #pragma unroll
                for (int v = 0; v < 4; ++v) mx[v] = fmaxf(mx[v], __shfl_xor(mx[v], off));
            #pragma unroll
            for (int v = 0; v < 4; ++v) {
                float mn = fmaxf(m[v], mx[v]);
                float scl = exp2f(m[v] - mn);
                m[v] = mn;
                lsum[v] *= scl;
                #pragma unroll
                for (int nf2 = 0; nf2 < 8; ++nf2) O[nf2][v] *= scl;
            }
        }
        #pragma unroll
        for (int nf = 0; nf < 4; ++nf)
            #pragma unroll
            for (int v = 0; v < 4; ++v) {
                float p = exp2f(z[nf][v] - m[v]);    // <= 256
                lsum[v] += p;
                union { float f; unsigned u; } pu; pu.f = p;
                const int row = 4 * g + v;
                const int bo = (row * 128 + (nf * 16 + c) * 2) ^ ((row & 7) << 4);
                *(short*)(Pbase + bo) = (short)(pu.u >> 16);   // RTZ
            }
        if (t < 7) asm volatile("s_waitcnt vmcnt(4)" ::: "memory");
        else       asm volatile("s_waitcnt vmcnt(0)" ::: "memory");
        __builtin_amdgcn_s_barrier();         // all waves' V(t) visible
        // ---- PV from LDS (own P region; same-wave ordering via lgkmcnt) ----
        bf16x8 pa[2];
        #pragma unroll
        for (int ks = 0; ks < 2; ++ks) {
            const int bo = (c * 128 + ks * 64 + g * 16) ^ ((c & 7) << 4);
            pa[ks] = *reinterpret_cast<const bf16x8*>(Pbase + bo);
        }
        #pragma unroll
        for (int nf2 = 0; nf2 < 8; ++nf2) {
            const int dh = nf2 * 16 + c;
            const char* vr = VldsB + dh * 128;
            const int sw = (dh & 7) << 4;
            #pragma unroll
            for (int ks = 0; ks < 2; ++ks) {
                bf16x8 vf = *reinterpret_cast<const bf16x8*>(vr + ((ks * 64 + g * 16) ^ sw));
                O[nf2] = __builtin_amdgcn_mfma_f32_16x16x32_bf16(pa[ks], vf, O[nf2], 0, 0, 0);
            }
        }
        __builtin_amdgcn_s_barrier();         // all PV reads done -> V free
        if (t < 7) stageV(sp * 8 + t + 1);    // hides under next QK+softmax
    }
    // epilogue: one cross-lane sum reduce for lsum
    #pragma unroll
    for (int off = 1; off <= 8; off <<= 1)
        #pragma unroll
        for (int v = 0; v < 4; ++v) lsum[v] += __shfl_xor(lsum[v], off);
    const size_t pbase = ((size_t)hd * NSPLIT + sp) * N_NODES;
    #pragma unroll
    for (int v = 0; v < 4; ++v) {
        const int row = q0 + 4 * g + v;
        const size_t rowo = (pbase + row) * 128;
        #pragma unroll
        for (int nf2 = 0; nf2 < 8; ++nf2)
            Opart[rowo + nf2 * 16 + c] = f2b(O[nf2][v]);
        if (c == 0) {
            ml[(pbase + row) * 2 + 0] = m[v];       // log2 units
            ml[(pbase + row) * 2 + 1] = lsum[v];
        }
    }
}

// combine NSPLIT partials -> attnb; grid 4096 x 256 thr (hd = tid>>7)
__global__ __launch_bounds__(256)
void attn_combine_kernel(const short* __restrict__ Opart, const float* __restrict__ ml,
                         short* __restrict__ attnb)
{
    const int row = blockIdx.x;
    const int hd = threadIdx.x >> 7, d = threadIdx.x & 127;
    float ms[NSPLIT], ls[NSPLIT];
    float mmax = -1e30f;
    #pragma unroll
    for (int s = 0; s < NSPLIT; ++s) {
        const size_t p = ((size_t)hd * NSPLIT + s) * N_NODES + row;
        ms[s] = ml[p * 2 + 0];
        ls[s] = ml[p * 2 + 1];
        mmax = fmaxf(mmax, ms[s]);
    }
    float lt = 0.f, acc = 0.f;
    #pragma unroll
    for (int s = 0; s < NSPLIT; ++s) {
        const float wgt = exp2f(ms[s] - mmax);
        lt += wgt * ls[s];
        const size_t p = ((size_t)hd * NSPLIT + s) * N_NODES + row;
        union { short s; unsigned short u; } b; b.s = Opart[p * 128 + d];
        union { unsigned u; float f; } cv; cv.u = ((unsigned)b.u) << 16;
        acc += wgt * cv.f;
    }
    attnb[(size_t)row * DM_ + hd * 128 + d] = f2b(acc / lt);
}

// ---------------------------------------------------------------------------
// GCN: degree accum (deg/count pre-zeroed by the big memset), CSR build.
// ---------------------------------------------------------------------------
__global__ void deg_accum_kernel(const int* __restrict__ dst,
                                 const float* __restrict__ w,
                                 float* deg, int* count) {
    int e = blockIdx.x * 256 + threadIdx.x;
    if (e < E_EDGES) {
        int d = dst[e];
        atomicAdd(&deg[d], w[e]);
        atomicAdd(&count[d], 1);
    }
}
// scan of count -> start/cursor (1024 thr, 4 elems each); deg -> rsqrt(deg+1)
__global__ __launch_bounds__(1024)
void csr_scan_kernel(const int* __restrict__ count, int* __restrict__ start,
                     int* __restrict__ cursor, float* __restrict__ deg) {
    __shared__ int sum[1024];
    const int tid = threadIdx.x;
    const int base = tid * 4;
    #pragma unroll
    for (int i = 0; i < 4; ++i) {
        int n = base + i;
        deg[n] = rsqrtf(deg[n] + 1.0f);       // fold self-loop weight
    }
    int loc[4]; int s = 0;
    #pragma unroll
    for (int i = 0; i < 4; ++i) { loc[i] = count[base + i]; s += loc[i]; }
    sum[tid] = s;
    __syncthreads();
    for (int off = 1; off < 1024; off <<= 1) {
        int v = (tid >= off) ? sum[tid - off] : 0;
        __syncthreads();
        sum[tid] += v;
        __syncthreads();
    }
    int run = sum[tid] - s;
    #pragma unroll
    for (int i = 0; i < 4; ++i) {
        start[base + i] = run;
        cursor[base + i] = run;
        run += loc[i];
    }
    if (tid == 1023) start[N_NODES] = run;
}
__global__ void csr_fill_kernel(const int* __restrict__ src, const int* __restrict__ dst,
                                const float* __restrict__ w, const float* __restrict__ dinv,
                                int* __restrict__ cursor,
                                int* __restrict__ csr_src, float* __restrict__ csr_nrm) {
    int e = blockIdx.x * 256 + threadIdx.x;
    if (e >= E_EDGES) return;
    int s = src[e], d = dst[e];
    int pos = atomicAdd(&cursor[d], 1);
    csr_src[pos] = s;
    csr_nrm[pos] = dinv[s] * w[e] * dinv[d];
}
// one block per dst node. 4 waves split the neighbor list; lanes own 4 dims.
// xwb is bf16 (int2 loads, unpack via shifts) -> half the scattered traffic.
__global__ __launch_bounds__(256)
void gcn_gather_kernel(const int* __restrict__ start, const int* __restrict__ csr_src,
                       const float* __restrict__ csr_nrm, const short* __restrict__ xwb,
                       const float* __restrict__ dinv, const float* __restrict__ b,
                       float* __restrict__ h, short* __restrict__ hb) {
    const int n = blockIdx.x, tid = threadIdx.x;
    const int q = tid >> 6, lane = tid & 63;
    const int s0 = start[n], s1 = start[n + 1];
    __shared__ int    ssrc[256];
    __shared__ float  snrm[256];
    __shared__ float4 red[4][64];
    float4 acc = {0.f, 0.f, 0.f, 0.f};
    for (int base = s0; base < s1; base += 256) {
        const int cnt = min(256, s1 - base);
        __syncthreads();
        if (tid < cnt) { ssrc[tid] = csr_src[base + tid]; snrm[tid] = csr_nrm[base + tid]; }
        __syncthreads();
        for (int j = q; j < cnt; j += 4) {
            const int2 pv = *reinterpret_cast<const int2*>(
                xwb + (size_t)ssrc[j] * DM_ + lane * 4);
            union { int i; float f; } e0, e1, e2, e3;
            e0.i = pv.x << 16; e1.i = pv.x & 0xffff0000;
            e2.i = pv.y << 16; e3.i = pv.y & 0xffff0000;
            const float wj = snrm[j];
            acc.x = fmaf(wj, e0.f, acc.x);
            acc.y = fmaf(wj, e1.f, acc.y);
            acc.z = fmaf(wj, e2.f, acc.z);
            acc.w = fmaf(wj, e3.f, acc.w);
        }
    }
    red[q][lane] = acc;
    __syncthreads();
    if (q == 0) {
        const float4 a1 = red[1][lane], a2 = red[2][lane], a3 = red[3][lane];
        const float di = dinv[n], d2 = di * di;
        const int2 pv = *reinterpret_cast<const int2*>(
            xwb + (size_t)n * DM_ + lane * 4);
        union { int i; float f; } x0, x1, x2, x3;
        x0.i = pv.x << 16; x1.i = pv.x & 0xffff0000;
        x2.i = pv.y << 16; x3.i = pv.y & 0xffff0000;
        const float4 bv = *reinterpret_cast<const float4*>(b + lane * 4);
        float v0 = fmaxf(acc.x + a1.x + a2.x + a3.x + d2 * x0.f + bv.x, 0.f);
        float v1 = fmaxf(acc.y + a1.y + a2.y + a3.y + d2 * x1.f + bv.y, 0.f);
        float v2 = fmaxf(acc.z + a1.z + a2.z + a3.z + d2 * x2.f + bv.z, 0.f);
        float v3 = fmaxf(acc.w + a1.w + a2.w + a3.w + d2 * x3.f + bv.w, 0.f);
        const size_t o = (size_t)n * DM_ + lane * 4;
        *reinterpret_cast<float4*>(h + o) = make_float4(v0, v1, v2, v3);
        union { short s[4]; int2 v; } ob;
        ob.s[0] = f2b(v0); ob.s[1] = f2b(v1); ob.s[2] = f2b(v2); ob.s[3] = f2b(v3);
        *reinterpret_cast<int2*>(hb + o) = ob.v;
    }
}

// ---------------------------------------------------------------------------
// LayerNorm(a+b); writes f32 + optional bf16; optionally re-zeroes clearbuf.
// ---------------------------------------------------------------------------
__global__ __launch_bounds__(256)
void ln_kernel(const float* __restrict__ a, const float* __restrict__ b,
               const float* __restrict__ g, const float* __restrict__ be,
               float* __restrict__ outf, short* __restrict__ outb,
               float* __restrict__ clearbuf) {
    const int n = blockIdx.x, d = threadIdx.x;
    const size_t idx = (size_t)n * DM_ + d;
    float x = a[idx] + b[idx];
    if (clearbuf) clearbuf[idx] = 0.f;
    float s = x;
    #pragma unroll
    for (int off = 32; off; off >>= 1) s += __shfl_xor(s, off);
    __shared__ float red[8];
    const int wid = d >> 6;
    if ((d & 63) == 0) red[wid] = s;
    __syncthreads();
    float mu = (red[0] + red[1] + red[2] + red[3]) * (1.f / 256.f);
    float c = x - mu;
    float q = c * c;
    #pragma unroll
    for (int off = 32; off; off >>= 1) q += __shfl_xor(q, off);
    if ((d & 63) == 0) red[4 + wid] = q;
    __syncthreads();
    float var = (red[4] + red[5] + red[6] + red[7]) * (1.f / 256.f);
    float v = c * rsqrtf(var + EPS_) * g[d] + be[d];
    outf[idx] = v;
    if (outb) outb[idx] = f2b(v);
}

// ---------------------------------------------------------------------------
extern "C" void kernel_launch(void* const* d_in, const int* in_sizes, int n_in,
                              void* d_out, int out_size, void* d_ws, size_t ws_size,
                              hipStream_t stream) {
    const float* x   = (const float*)d_in[0];
    const int*   ei  = (const int*)  d_in[1];
    const float* ew  = (const float*)d_in[2];
    const float* Wg  = (const float*)d_in[3];
    const float* bg  = (const float*)d_in[4];
    const float* inw = (const float*)d_in[5];
    const float* inb = (const float*)d_in[6];
    const float* ow  = (const float*)d_in[7];
    const float* ob  = (const float*)d_in[8];
    const float* l1w = (const float*)d_in[9];
    const float* l1b = (const float*)d_in[10];
    const float* l2w = (const float*)d_in[11];
    const float* l2b = (const float*)d_in[12];
    const float* g1  = (const float*)d_in[13];
    const float* b1  = (const float*)d_in[14];
    const float* g2  = (const float*)d_in[15];
    const float* b2  = (const float*)d_in[16];
    float* out = (float*)d_out;

    char* ws = (char*)d_ws;
    size_t off = 0;
    auto alloc = [&](size_t bytes) {
        void* p = ws + off;
        off += (bytes + 255) & ~(size_t)255;
        return p;
    };
    // zero-initialized region (one memset): deg | count | xw | tmp
    float* deg   = (float*)alloc((size_t)N_NODES * 4);
    int*   count = (int*)  alloc((size_t)N_NODES * 4);
    float* xw    = (float*)alloc((size_t)N_NODES * DM_ * 4);           // 4 MB
    float* tmp   = (float*)alloc((size_t)N_NODES * DM_ * 4);           // 4 MB
    size_t zspan = off;
    int*   startA  = (int*)  alloc((size_t)(N_NODES + 1) * 4);
    int*   cursor  = (int*)  alloc((size_t)N_NODES * 4);
    int*   csr_src = (int*)  alloc((size_t)E_EDGES * 4);
    float* csr_nrm = (float*)alloc((size_t)E_EDGES * 4);
    short* xb    = (short*)alloc((size_t)N_NODES * DIN_ * 2);          // 4 MB
    short* WgT   = (short*)alloc((size_t)DM_ * DIN_ * 2);
    short* inwb  = (short*)alloc((size_t)768 * DM_ * 2);
    short* owb   = (short*)alloc((size_t)DM_ * DM_ * 2);
    short* l1wb  = (short*)alloc((size_t)DFF_ * DM_ * 2);
    short* l2wb  = (short*)alloc((size_t)DM_ * DFF_ * 2);
    short* xwb   = (short*)alloc((size_t)N_NODES * DM_ * 2);           // 2 MB
    float* h     = (float*)alloc((size_t)N_NODES * DM_ * 4);
    short* hb    = (short*)alloc((size_t)N_NODES * DM_ * 2);
    short* qkvb  = (short*)alloc((size_t)N_NODES * 768 * 2);           // 6 MB
    short* VT    = (short*)alloc((size_t)DM_ * N_NODES * 2);           // 2 MB
    short* attnb = (short*)alloc((size_t)N_NODES * DM_ * 2);
    float* h1    = (float*)alloc((size_t)N_NODES * DM_ * 4);
    short* h1b   = (short*)alloc((size_t)N_NODES * DM_ * 2);
    size_t opart_b = (size_t)2 * NSPLIT * N_NODES * 128 * 2;           // 16.8 MB
    size_t ml_b    = (size_t)2 * NSPLIT * N_NODES * 2 * 4;             // 0.5 MB
    size_t ff1_b   = (size_t)N_NODES * DFF_ * 2;                       // 16 MB
    char*  R     = (char*)alloc(opart_b + ml_b > ff1_b ? opart_b + ml_b : ff1_b);
    short* Opart = (short*)R;
    float* ml    = (float*)(R + opart_b);
    short* ff1b  = (short*)R;
    (void)ws_size; (void)in_sizes; (void)n_in; (void)out_size;

    const int* srcI = ei;
    const int* dstI = ei + E_EDGES;

    // ---- one upfront memset + merged casts ----
    hipMemsetAsync(ws, 0, zspan, stream);
    castall_kernel<<<3456, 256, 0, stream>>>(x, xb, inw, inwb, ow, owb,
                                             l1w, l1wb, l2w, l2wb, Wg, WgT);

    // ---- GCN ----
    deg_accum_kernel<<<E_EDGES / 256, 256, 0, stream>>>(dstI, ew, deg, count);
    csr_scan_kernel<<<1, 1024, 0, stream>>>(count, startA, cursor, deg);
    csr_fill_kernel<<<E_EDGES / 256, 256, 0, stream>>>(srcI, dstI, ew, deg, cursor,
                                                       csr_src, csr_nrm);
    mgemm_kernel<128, false, false, true><<<dim3(2, 32, 4), 256, 0, stream>>>(
        xb, WgT, nullptr, xw, nullptr, nullptr,
        N_NODES, DM_, DIN_, DIN_, DIN_, DM_, 128);
    castxw_kernel<<<1024, 256, 0, stream>>>(xw, xwb);
    gcn_gather_kernel<<<N_NODES, 256, 0, stream>>>(startA, csr_src, csr_nrm, xwb,
                                                   deg, bg, h, hb);

    // ---- QKV (MT=64 -> 384 blocks; V cols written transposed into VT) ----
    mgemm_kernel<64, true, false, false><<<dim3(6, 64), 256, 0, stream>>>(
        hb, inwb, inb, nullptr, qkvb, VT,
        N_NODES, 768, DM_, DM_, DM_, 768, 0);

    // ---- flash attention (all-resident) + combine ----
    fattn_kernel<<<1024, 256, 0, stream>>>(qkvb, VT, Opart, ml);
    attn_combine_kernel<<<N_NODES, 256, 0, stream>>>(Opart, ml, attnb);

    // ---- out_proj (MT=64, split-K z=2 -> 256 blocks) + LN1 ----
    mgemm_kernel<64, false, false, true><<<dim3(2, 64, 2), 256, 0, stream>>>(
        attnb, owb, ob, tmp, nullptr, nullptr,
        N_NODES, DM_, DM_, DM_, DM_, DM_, 128);
    ln_kernel<<<N_NODES, 256, 0, stream>>>(h, tmp, g1, b1, h1, h1b, tmp);

    // ---- FFN ----
    mgemm_kernel<128, true, true, false><<<dim3(16, 32), 256, 0, stream>>>(
        h1b, l1wb, l1b, nullptr, ff1b, nullptr,
        N_NODES, DFF_, DM_, DM_, DM_, DFF_, 0);
    mgemm_kernel<128, false, false, true><<<dim3(2, 32, 4), 256, 0, stream>>>(
        ff1b, l2wb, l2b, tmp, nullptr, nullptr,
        N_NODES, DM_, DFF_, DFF_, DFF_, DM_, 512);
    ln_kernel<<<N_NODES, 256, 0, stream>>>(h1, tmp, g2, b2, out, nullptr, nullptr);
}

// Round 16
// 173.846 us; speedup vs baseline: 1.0897x; 1.0897x over previous
//
#include <hip/hip_runtime.h>
#include <hip/hip_bf16.h>

#define N_NODES 4096
#define E_EDGES 131072
#define DIN_    512
#define DM_     256
#define DFF_    2048
#define EPS_    1e-5f
#define NSPLIT  8

typedef __attribute__((ext_vector_type(8))) short bf16x8;   // 8 bf16 = 4 VGPR
typedef __attribute__((ext_vector_type(4))) float f32x4;

__device__ __forceinline__ short f2b(float f) {
    union { float f; unsigned u; } x; x.f = f;
    unsigned r = x.u + 0x7fff + ((x.u >> 16) & 1);   // RNE
    return (short)(r >> 16);
}

// async global->LDS, 16B per lane; lptr must be wave-uniform (HW adds lane*16)
__device__ __forceinline__ void gload16(const void* g, void* l) {
    __builtin_amdgcn_global_load_lds(
        (const __attribute__((address_space(1))) void*)g,
        (__attribute__((address_space(3))) void*)l, 16, 0, 0);
}

// ---------------------------------------------------------------------------
// merged f32->bf16 casts + W_gcn transpose, one launch.
// ---------------------------------------------------------------------------
__global__ __launch_bounds__(256)
void castall_kernel(const float* __restrict__ x, short* __restrict__ xb,
                    const float* __restrict__ inw, short* __restrict__ inwb,
                    const float* __restrict__ ow, short* __restrict__ owb,
                    const float* __restrict__ l1w, short* __restrict__ l1wb,
                    const float* __restrict__ l2w, short* __restrict__ l2wb,
                    const float* __restrict__ Wg, short* __restrict__ WgT) {
    const int b = blockIdx.x;
    __shared__ float t[32][33];
    if (b >= 3328) {                       // W_gcn [512][256] -> WgT [256][512]
        const int b2 = b - 3328;
        const int bk = (b2 & 15) * 32, bn = (b2 >> 4) * 32;
        const int tx = threadIdx.x & 31, ty = threadIdx.x >> 5;
        #pragma unroll
        for (int i = 0; i < 4; ++i) {
            int r = ty + i * 8;
            t[r][tx] = Wg[(size_t)(bk + r) * DM_ + bn + tx];
        }
        __syncthreads();
        #pragma unroll
        for (int i = 0; i < 4; ++i) {
            int r = ty + i * 8;
            WgT[(size_t)(bn + r) * DIN_ + bk + tx] = f2b(t[tx][r]);
        }
        return;
    }
    const float* s; short* d; int base;
    if (b < 2048)      { s = x;   d = xb;   base = b * 256; }
    else if (b < 2240) { s = inw; d = inwb; base = (b - 2048) * 256; }
    else if (b < 2304) { s = ow;  d = owb;  base = (b - 2240) * 256; }
    else if (b < 2816) { s = l1w; d = l1wb; base = (b - 2304) * 256; }
    else               { s = l2w; d = l2wb; base = (b - 2816) * 256; }
    const int i = base + threadIdx.x;
    float4 v = reinterpret_cast<const float4*>(s)[i];
    union { short s[4]; int2 v; } o;
    o.s[0] = f2b(v.x); o.s[1] = f2b(v.y); o.s[2] = f2b(v.z); o.s[3] = f2b(v.w);
    reinterpret_cast<int2*>(d)[i] = o.v;
}

// ---------------------------------------------------------------------------
// bf16 MFMA GEMM, 2-phase double-buffered, M-tile templated (MT = 128 or 64).
// ---------------------------------------------------------------------------
template<int MT, bool BF16OUT, bool RELU, bool SPLITK>
__global__ __launch_bounds__(256)
void mgemm_kernel(const short* __restrict__ A, const short* __restrict__ B,
                  const float* __restrict__ bias,
                  float* __restrict__ Cf, short* __restrict__ Cb,
                  short* __restrict__ VTout,
                  int M, int N, int K, int lda, int ldb, int ldc, int kchunk)
{
    constexpr int MFN = MT / 32;                   // mf fragments per wave
    constexpr int ACH = MT / 64;                   // A-stage chunks per thread
    __shared__ __align__(16) short As[2][MT * 32];
    __shared__ __align__(16) short Bs[2][128 * 32];
    const int tid = threadIdx.x;
    const int lane = tid & 63, w = tid >> 6;
    const int c = lane & 15, g = lane >> 4;
    const int wm = (w >> 1) * (MT / 2), wn = (w & 1) * 64;
    const int bm = blockIdx.y * MT, bn = blockIdx.x * 128;
    int k0 = 0, kend = K;
    if (SPLITK) { k0 = blockIdx.z * kchunk; kend = min(K, k0 + kchunk); }

    const int wbase = (tid & ~63) * 16;            // wave-uniform LDS byte base
    int srowA[ACH], soffA[ACH];
    #pragma unroll
    for (int i = 0; i < ACH; ++i) {
        int L = i * 256 + tid;
        srowA[i] = L >> 2;
        soffA[i] = ((L & 3) ^ ((srowA[i] >> 1) & 3)) * 8;   // shorts
    }
    int srowB[2], soffB[2];
    #pragma unroll
    for (int i = 0; i < 2; ++i) {
        int L = i * 256 + tid;
        srowB[i] = L >> 2;
        soffB[i] = ((L & 3) ^ ((srowB[i] >> 1) & 3)) * 8;
    }

    auto stage = [&](int b, int kb) {
        #pragma unroll
        for (int i = 0; i < ACH; ++i)
            gload16(A + (size_t)(bm + srowA[i]) * lda + kb + soffA[i],
                    (char*)As[b] + i * 4096 + wbase);
        #pragma unroll
        for (int i = 0; i < 2; ++i)
            gload16(B + (size_t)(bn + srowB[i]) * ldb + kb + soffB[i],
                    (char*)Bs[b] + i * 4096 + wbase);
    };

    const int nsteps = (kend - k0) >> 5;
    f32x4 acc[MFN][4] = {};
    stage(0, k0);
    for (int s = 0; s < nsteps; ++s) {
        const int cur = s & 1;
        const bool pf = (s + 1 < nsteps);
        if (pf) stage(cur ^ 1, k0 + (s + 1) * 32);    // WAR-safe: drained at s-1 bar2
        if (pf) {
            if constexpr (ACH == 2) asm volatile("s_waitcnt vmcnt(4)" ::: "memory");
            else                    asm volatile("s_waitcnt vmcnt(3)" ::: "memory");
        } else {
            asm volatile("s_waitcnt vmcnt(0)" ::: "memory");
        }
        __builtin_amdgcn_s_barrier();                 // all waves' cur landed
        bf16x8 af[MFN], bf[4];
        #pragma unroll
        for (int mf = 0; mf < MFN; ++mf) {
            int r = wm + mf * 16 + c;
            int sw = (g ^ ((r >> 1) & 3)) * 16;
            af[mf] = *reinterpret_cast<const bf16x8*>((const char*)As[cur] + r * 64 + sw);
        }
        #pragma unroll
        for (int nf = 0; nf < 4; ++nf) {
            int r = wn + nf * 16 + c;
            int sw = (g ^ ((r >> 1) & 3)) * 16;
            bf[nf] = *reinterpret_cast<const bf16x8*>((const char*)Bs[cur] + r * 64 + sw);
        }
        #pragma unroll
        for (int mf = 0; mf < MFN; ++mf)
            #pragma unroll
            for (int nf = 0; nf < 4; ++nf)
                acc[mf][nf] = __builtin_amdgcn_mfma_f32_16x16x32_bf16(
                    af[mf], bf[nf], acc[mf][nf], 0, 0, 0);
        __builtin_amdgcn_s_barrier();                 // all reads of cur done
    }
    #pragma unroll
    for (int mf = 0; mf < MFN; ++mf) {
        const int row = bm + wm + mf * 16 + g * 4;
        #pragma unroll
        for (int nf = 0; nf < 4; ++nf) {
            const int col = bn + wn + nf * 16 + c;
            float bv = bias ? bias[col] : 0.f;
            #pragma unroll
            for (int v = 0; v < 4; ++v) {
                float val = acc[mf][nf][v];
                size_t o = (size_t)(row + v) * ldc + col;
                if (SPLITK) {
                    if (blockIdx.z == 0) val += bv;
                    atomicAdd(&Cf[o], val);
                } else {
                    val += bv;
                    if (RELU) val = fmaxf(val, 0.f);
                    if (BF16OUT) {
                        short bvs = f2b(val);
                        Cb[o] = bvs;
                        if (VTout && col >= 512)
                            VTout[(size_t)(col - 512) * N_NODES + row + v] = bvs;
                    } else {
                        Cf[o] = val;
                    }
                }
            }
        }
    }
}

// ---------------------------------------------------------------------------
// Flash attention (unchanged -- control).
// ---------------------------------------------------------------------------
__global__ __launch_bounds__(256)
void fattn_kernel(const short* __restrict__ qkv, const short* __restrict__ VT,
                  short* __restrict__ Opart, float* __restrict__ ml)
{
    const int bid = blockIdx.x;
    const int j = bid >> 3;
    const int pair = 2 * (bid & 7) + (j & 1);
    const int hd = pair >> 3, sp = pair & 7;
    const int qt = j >> 1;
    const int tid = threadIdx.x;
    const int w = tid >> 6, lane = tid & 63;
    const int c = lane & 15, g = lane >> 4;
    const int q0 = qt * 64 + w * 16;

    __shared__ __align__(16) char smem[40960];   // K 16K | V 16K | P 4x2048
    char* KldsB = smem;
    char* VldsB = smem + 16384;
    char* Pbase = smem + 32768 + w * 2048;       // [16][64] XOR-swizzled

    const char* qkvC = (const char*)qkv;
    const char* vtC  = (const char*)VT;
    const int wbase = (tid & ~63) * 16;          // wave-uniform LDS chunk base

    const short* Q = qkv + (size_t)q0 * 768 + hd * 128;
    bf16x8 qf[4];
    #pragma unroll
    for (int ks = 0; ks < 4; ++ks)
        qf[ks] = *reinterpret_cast<const bf16x8*>(Q + (size_t)c * 768 + ks * 32 + g * 8);

    auto stageK = [&](int kt) {
        const int key0 = kt * 64;
        #pragma unroll
        for (int i = 0; i < 4; ++i) {
            int Lr  = i * 4096 + tid * 16;
            int key = Lr >> 8;
            int lg  = (Lr & 255) ^ ((key & 7) << 4);
            const char* src = qkvC + ((size_t)(key0 + key) * 768 + 256 + hd * 128) * 2 + lg;
            gload16(src, KldsB + i * 4096 + wbase);
        }
    };
    auto stageV = [&](int kt) {
        const int key0 = kt * 64;
        #pragma unroll
        for (int i = 0; i < 4; ++i) {
            int Lr = i * 4096 + tid * 16;
            int dh = Lr >> 7;
            int lg = (Lr & 127) ^ ((dh & 7) << 4);
            const char* src = vtC + (size_t)(hd * 128 + dh) * 8192 + key0 * 2 + lg;
            gload16(src, VldsB + i * 4096 + wbase);
        }
    };

    f32x4 O[8] = {};
    float m[4]  = {-1e30f, -1e30f, -1e30f, -1e30f};
    float lsum[4] = {};                       // per-lane partial row sums
    const float C = 0.12751744f;              // log2(e)/sqrt(128)

    stageK(sp * 8);
    stageV(sp * 8);

    for (int t = 0; t < 8; ++t) {
        asm volatile("s_waitcnt vmcnt(4)" ::: "memory");
        __builtin_amdgcn_s_barrier();         // all waves' K(t) visible
        // ---- QK^T from LDS ----
        f32x4 S[4] = {};
        #pragma unroll
        for (int nf = 0; nf < 4; ++nf) {
            const int key = nf * 16 + c;
            const char* kr = KldsB + key * 256;
            const int sw = (key & 7) << 4;
            #pragma unroll
            for (int ks = 0; ks < 4; ++ks) {
                bf16x8 kf = *reinterpret_cast<const bf16x8*>(kr + ((ks * 64 + g * 16) ^ sw));
                S[nf] = __builtin_amdgcn_mfma_f32_16x16x32_bf16(qf[ks], kf, S[nf], 0, 0, 0);
            }
        }
        __builtin_amdgcn_s_barrier();         // all QK reads done -> K free
        if (t < 7) stageK(sp * 8 + t + 1);    // hides under softmax+PV

        // ---- online softmax, defer-max (log2 units, per-lane lsum) ----
        float z[4][4];
        float lmax[4];
        bool ok = true;
        #pragma unroll
        for (int v = 0; v < 4; ++v) {
            #pragma unroll
            for (int nf = 0; nf < 4; ++nf) z[nf][v] = S[nf][v] * C;
            lmax[v] = fmaxf(fmaxf(z[0][v], z[1][v]), fmaxf(z[2][v], z[3][v]));
            ok = ok && (lmax[v] <= m[v] + 8.f);
        }
        if (!__all(ok)) {                     // rare after tile 0
            float mx[4];
            #pragma unroll
            for (int v = 0; v < 4; ++v) mx[v] = lmax[v];
            #pragma unroll
            for (int off = 1; off <= 8; off <<= 1)
                #pragma unroll
                for (int v = 0; v < 4; ++v) mx[v] = fmaxf(mx[v], __shfl_xor(mx[v], off));
            #pragma unroll
            for (int v = 0; v < 4; ++v) {
                float mn = fmaxf(m[v], mx[v]);
                float scl = exp2f(m[v] - mn);
                m[v] = mn;
                lsum[v] *= scl;
                #pragma unroll
                for (int nf2 = 0; nf2 < 8; ++nf2) O[nf2][v] *= scl;
            }
        }
        #pragma unroll
        for (int nf = 0; nf < 4; ++nf)
            #pragma unroll
            for (int v = 0; v < 4; ++v) {
                float p = exp2f(z[nf][v] - m[v]);    // <= 256
                lsum[v] += p;
                union { float f; unsigned u; } pu; pu.f = p;
                const int row = 4 * g + v;
                const int bo = (row * 128 + (nf * 16 + c) * 2) ^ ((row & 7) << 4);
                *(short*)(Pbase + bo) = (short)(pu.u >> 16);   // RTZ
            }
        if (t < 7) asm volatile("s_waitcnt vmcnt(4)" ::: "memory");
        else       asm volatile("s_waitcnt vmcnt(0)" ::: "memory");
        __builtin_amdgcn_s_barrier();         // all waves' V(t) visible
        // ---- PV from LDS (own P region; same-wave ordering via lgkmcnt) ----
        bf16x8 pa[2];
        #pragma unroll
        for (int ks = 0; ks < 2; ++ks) {
            const int bo = (c * 128 + ks * 64 + g * 16) ^ ((c & 7) << 4);
            pa[ks] = *reinterpret_cast<const bf16x8*>(Pbase + bo);
        }
        #pragma unroll
        for (int nf2 = 0; nf2 < 8; ++nf2) {
            const int dh = nf2 * 16 + c;
            const char* vr = VldsB + dh * 128;
            const int sw = (dh & 7) << 4;
            #pragma unroll
            for (int ks = 0; ks < 2; ++ks) {
                bf16x8 vf = *reinterpret_cast<const bf16x8*>(vr + ((ks * 64 + g * 16) ^ sw));
                O[nf2] = __builtin_amdgcn_mfma_f32_16x16x32_bf16(pa[ks], vf, O[nf2], 0, 0, 0);
            }
        }
        __builtin_amdgcn_s_barrier();         // all PV reads done -> V free
        if (t < 7) stageV(sp * 8 + t + 1);    // hides under next QK+softmax
    }
    // epilogue: one cross-lane sum reduce for lsum
    #pragma unroll
    for (int off = 1; off <= 8; off <<= 1)
        #pragma unroll
        for (int v = 0; v < 4; ++v) lsum[v] += __shfl_xor(lsum[v], off);
    const size_t pbase = ((size_t)hd * NSPLIT + sp) * N_NODES;
    #pragma unroll
    for (int v = 0; v < 4; ++v) {
        const int row = q0 + 4 * g + v;
        const size_t rowo = (pbase + row) * 128;
        #pragma unroll
        for (int nf2 = 0; nf2 < 8; ++nf2)
            Opart[rowo + nf2 * 16 + c] = f2b(O[nf2][v]);
        if (c == 0) {
            ml[(pbase + row) * 2 + 0] = m[v];       // log2 units
            ml[(pbase + row) * 2 + 1] = lsum[v];
        }
    }
}

// combine NSPLIT partials -> attnb; grid 4096 x 256 thr (hd = tid>>7)
__global__ __launch_bounds__(256)
void attn_combine_kernel(const short* __restrict__ Opart, const float* __restrict__ ml,
                         short* __restrict__ attnb)
{
    const int row = blockIdx.x;
    const int hd = threadIdx.x >> 7, d = threadIdx.x & 127;
    float ms[NSPLIT], ls[NSPLIT];
    float mmax = -1e30f;
    #pragma unroll
    for (int s = 0; s < NSPLIT; ++s) {
        const size_t p = ((size_t)hd * NSPLIT + s) * N_NODES + row;
        ms[s] = ml[p * 2 + 0];
        ls[s] = ml[p * 2 + 1];
        mmax = fmaxf(mmax, ms[s]);
    }
    float lt = 0.f, acc = 0.f;
    #pragma unroll
    for (int s = 0; s < NSPLIT; ++s) {
        const float wgt = exp2f(ms[s] - mmax);
        lt += wgt * ls[s];
        const size_t p = ((size_t)hd * NSPLIT + s) * N_NODES + row;
        union { short s; unsigned short u; } b; b.s = Opart[p * 128 + d];
        union { unsigned u; float f; } cv; cv.u = ((unsigned)b.u) << 16;
        acc += wgt * cv.f;
    }
    attnb[(size_t)row * DM_ + hd * 128 + d] = f2b(acc / lt);
}

// ---------------------------------------------------------------------------
// GCN: degree accum (deg/count pre-zeroed by the small memset), CSR build.
// ---------------------------------------------------------------------------
__global__ void deg_accum_kernel(const int* __restrict__ dst,
                                 const float* __restrict__ w,
                                 float* deg, int* count) {
    int e = blockIdx.x * 256 + threadIdx.x;
    if (e < E_EDGES) {
        int d = dst[e];
        atomicAdd(&deg[d], w[e]);
        atomicAdd(&count[d], 1);
    }
}
// scan of count -> start/cursor (1024 thr, 4 elems each); deg -> rsqrt(deg+1)
__global__ __launch_bounds__(1024)
void csr_scan_kernel(const int* __restrict__ count, int* __restrict__ start,
                     int* __restrict__ cursor, float* __restrict__ deg) {
    __shared__ int sum[1024];
    const int tid = threadIdx.x;
    const int base = tid * 4;
    #pragma unroll
    for (int i = 0; i < 4; ++i) {
        int n = base + i;
        deg[n] = rsqrtf(deg[n] + 1.0f);       // fold self-loop weight
    }
    int loc[4]; int s = 0;
    #pragma unroll
    for (int i = 0; i < 4; ++i) { loc[i] = count[base + i]; s += loc[i]; }
    sum[tid] = s;
    __syncthreads();
    for (int off = 1; off < 1024; off <<= 1) {
        int v = (tid >= off) ? sum[tid - off] : 0;
        __syncthreads();
        sum[tid] += v;
        __syncthreads();
    }
    int run = sum[tid] - s;
    #pragma unroll
    for (int i = 0; i < 4; ++i) {
        start[base + i] = run;
        cursor[base + i] = run;
        run += loc[i];
    }
    if (tid == 1023) start[N_NODES] = run;
}
__global__ void csr_fill_kernel(const int* __restrict__ src, const int* __restrict__ dst,
                                const float* __restrict__ w, const float* __restrict__ dinv,
                                int* __restrict__ cursor,
                                int* __restrict__ csr_src, float* __restrict__ csr_nrm) {
    int e = blockIdx.x * 256 + threadIdx.x;
    if (e >= E_EDGES) return;
    int s = src[e], d = dst[e];
    int pos = atomicAdd(&cursor[d], 1);
    csr_src[pos] = s;
    csr_nrm[pos] = dinv[s] * w[e] * dinv[d];
}
// one block per dst node. 4 waves split the neighbor list; lanes own 4 dims.
// xwb is bf16 (int2 loads, unpack via shifts).
__global__ __launch_bounds__(256)
void gcn_gather_kernel(const int* __restrict__ start, const int* __restrict__ csr_src,
                       const float* __restrict__ csr_nrm, const short* __restrict__ xwb,
                       const float* __restrict__ dinv, const float* __restrict__ b,
                       float* __restrict__ h, short* __restrict__ hb) {
    const int n = blockIdx.x, tid = threadIdx.x;
    const int q = tid >> 6, lane = tid & 63;
    const int s0 = start[n], s1 = start[n + 1];
    __shared__ int    ssrc[256];
    __shared__ float  snrm[256];
    __shared__ float4 red[4][64];
    float4 acc = {0.f, 0.f, 0.f, 0.f};
    for (int base = s0; base < s1; base += 256) {
        const int cnt = min(256, s1 - base);
        __syncthreads();
        if (tid < cnt) { ssrc[tid] = csr_src[base + tid]; snrm[tid] = csr_nrm[base + tid]; }
        __syncthreads();
        for (int j = q; j < cnt; j += 4) {
            const int2 pv = *reinterpret_cast<const int2*>(
                xwb + (size_t)ssrc[j] * DM_ + lane * 4);
            union { int i; float f; } e0, e1, e2, e3;
            e0.i = pv.x << 16; e1.i = pv.x & 0xffff0000;
            e2.i = pv.y << 16; e3.i = pv.y & 0xffff0000;
            const float wj = snrm[j];
            acc.x = fmaf(wj, e0.f, acc.x);
            acc.y = fmaf(wj, e1.f, acc.y);
            acc.z = fmaf(wj, e2.f, acc.z);
            acc.w = fmaf(wj, e3.f, acc.w);
        }
    }
    red[q][lane] = acc;
    __syncthreads();
    if (q == 0) {
        const float4 a1 = red[1][lane], a2 = red[2][lane], a3 = red[3][lane];
        const float di = dinv[n], d2 = di * di;
        const int2 pv = *reinterpret_cast<const int2*>(
            xwb + (size_t)n * DM_ + lane * 4);
        union { int i; float f; } x0, x1, x2, x3;
        x0.i = pv.x << 16; x1.i = pv.x & 0xffff0000;
        x2.i = pv.y << 16; x3.i = pv.y & 0xffff0000;
        const float4 bv = *reinterpret_cast<const float4*>(b + lane * 4);
        float v0 = fmaxf(acc.x + a1.x + a2.x + a3.x + d2 * x0.f + bv.x, 0.f);
        float v1 = fmaxf(acc.y + a1.y + a2.y + a3.y + d2 * x1.f + bv.y, 0.f);
        float v2 = fmaxf(acc.z + a1.z + a2.z + a3.z + d2 * x2.f + bv.z, 0.f);
        float v3 = fmaxf(acc.w + a1.w + a2.w + a3.w + d2 * x3.f + bv.w, 0.f);
        const size_t o = (size_t)n * DM_ + lane * 4;
        *reinterpret_cast<float4*>(h + o) = make_float4(v0, v1, v2, v3);
        union { short s[4]; int2 v; } ob;
        ob.s[0] = f2b(v0); ob.s[1] = f2b(v1); ob.s[2] = f2b(v2); ob.s[3] = f2b(v3);
        *reinterpret_cast<int2*>(hb + o) = ob.v;
    }
}

// ---------------------------------------------------------------------------
// LayerNorm(a+b); writes f32 + optional bf16; optionally re-zeroes clearbuf.
// ---------------------------------------------------------------------------
__global__ __launch_bounds__(256)
void ln_kernel(const float* __restrict__ a, const float* __restrict__ b,
               const float* __restrict__ g, const float* __restrict__ be,
               float* __restrict__ outf, short* __restrict__ outb,
               float* __restrict__ clearbuf) {
    const int n = blockIdx.x, d = threadIdx.x;
    const size_t idx = (size_t)n * DM_ + d;
    float x = a[idx] + b[idx];
    if (clearbuf) clearbuf[idx] = 0.f;
    float s = x;
    #pragma unroll
    for (int off = 32; off; off >>= 1) s += __shfl_xor(s, off);
    __shared__ float red[8];
    const int wid = d >> 6;
    if ((d & 63) == 0) red[wid] = s;
    __syncthreads();
    float mu = (red[0] + red[1] + red[2] + red[3]) * (1.f / 256.f);
    float c = x - mu;
    float q = c * c;
    #pragma unroll
    for (int off = 32; off; off >>= 1) q += __shfl_xor(q, off);
    if ((d & 63) == 0) red[4 + wid] = q;
    __syncthreads();
    float var = (red[4] + red[5] + red[6] + red[7]) * (1.f / 256.f);
    float v = c * rsqrtf(var + EPS_) * g[d] + be[d];
    outf[idx] = v;
    if (outb) outb[idx] = f2b(v);
}

// ---------------------------------------------------------------------------
extern "C" void kernel_launch(void* const* d_in, const int* in_sizes, int n_in,
                              void* d_out, int out_size, void* d_ws, size_t ws_size,
                              hipStream_t stream) {
    const float* x   = (const float*)d_in[0];
    const int*   ei  = (const int*)  d_in[1];
    const float* ew  = (const float*)d_in[2];
    const float* Wg  = (const float*)d_in[3];
    const float* bg  = (const float*)d_in[4];
    const float* inw = (const float*)d_in[5];
    const float* inb = (const float*)d_in[6];
    const float* ow  = (const float*)d_in[7];
    const float* ob  = (const float*)d_in[8];
    const float* l1w = (const float*)d_in[9];
    const float* l1b = (const float*)d_in[10];
    const float* l2w = (const float*)d_in[11];
    const float* l2b = (const float*)d_in[12];
    const float* g1  = (const float*)d_in[13];
    const float* b1  = (const float*)d_in[14];
    const float* g2  = (const float*)d_in[15];
    const float* b2  = (const float*)d_in[16];
    float* out = (float*)d_out;

    char* ws = (char*)d_ws;
    size_t off = 0;
    auto alloc = [&](size_t bytes) {
        void* p = ws + off;
        off += (bytes + 255) & ~(size_t)255;
        return p;
    };
    // zero-initialized region (one small memset): deg | count
    float* deg   = (float*)alloc((size_t)N_NODES * 4);
    int*   count = (int*)  alloc((size_t)N_NODES * 4);
    size_t zspan = off;
    float* tmp     = (float*)alloc((size_t)N_NODES * DM_ * 4);         // 4 MB
    int*   startA  = (int*)  alloc((size_t)(N_NODES + 1) * 4);
    int*   cursor  = (int*)  alloc((size_t)N_NODES * 4);
    int*   csr_src = (int*)  alloc((size_t)E_EDGES * 4);
    float* csr_nrm = (float*)alloc((size_t)E_EDGES * 4);
    short* xb    = (short*)alloc((size_t)N_NODES * DIN_ * 2);          // 4 MB
    short* WgT   = (short*)alloc((size_t)DM_ * DIN_ * 2);
    short* inwb  = (short*)alloc((size_t)768 * DM_ * 2);
    short* owb   = (short*)alloc((size_t)DM_ * DM_ * 2);
    short* l1wb  = (short*)alloc((size_t)DFF_ * DM_ * 2);
    short* l2wb  = (short*)alloc((size_t)DM_ * DFF_ * 2);
    short* xwb   = (short*)alloc((size_t)N_NODES * DM_ * 2);           // 2 MB
    float* h     = (float*)alloc((size_t)N_NODES * DM_ * 4);
    short* hb    = (short*)alloc((size_t)N_NODES * DM_ * 2);
    short* qkvb  = (short*)alloc((size_t)N_NODES * 768 * 2);           // 6 MB
    short* VT    = (short*)alloc((size_t)DM_ * N_NODES * 2);           // 2 MB
    short* attnb = (short*)alloc((size_t)N_NODES * DM_ * 2);
    float* h1    = (float*)alloc((size_t)N_NODES * DM_ * 4);
    short* h1b   = (short*)alloc((size_t)N_NODES * DM_ * 2);
    size_t opart_b = (size_t)2 * NSPLIT * N_NODES * 128 * 2;           // 16.8 MB
    size_t ml_b    = (size_t)2 * NSPLIT * N_NODES * 2 * 4;             // 0.5 MB
    size_t ff1_b   = (size_t)N_NODES * DFF_ * 2;                       // 16 MB
    char*  R     = (char*)alloc(opart_b + ml_b > ff1_b ? opart_b + ml_b : ff1_b);
    short* Opart = (short*)R;
    float* ml    = (float*)(R + opart_b);
    short* ff1b  = (short*)R;
    (void)ws_size; (void)in_sizes; (void)n_in; (void)out_size;

    const int* srcI = ei;
    const int* dstI = ei + E_EDGES;

    // ---- small memset (deg, count) + merged casts ----
    hipMemsetAsync(ws, 0, zspan, stream);
    castall_kernel<<<3456, 256, 0, stream>>>(x, xb, inw, inwb, ow, owb,
                                             l1w, l1wb, l2w, l2wb, Wg, WgT);

    // ---- GCN ----
    deg_accum_kernel<<<E_EDGES / 256, 256, 0, stream>>>(dstI, ew, deg, count);
    csr_scan_kernel<<<1, 1024, 0, stream>>>(count, startA, cursor, deg);
    csr_fill_kernel<<<E_EDGES / 256, 256, 0, stream>>>(srcI, dstI, ew, deg, cursor,
                                                       csr_src, csr_nrm);
    // xw: MT=64 non-split, bf16 out directly (no atomics, no zero, no cast)
    mgemm_kernel<64, true, false, false><<<dim3(2, 64), 256, 0, stream>>>(
        xb, WgT, nullptr, nullptr, xwb, nullptr,
        N_NODES, DM_, DIN_, DIN_, DIN_, DM_, 0);
    gcn_gather_kernel<<<N_NODES, 256, 0, stream>>>(startA, csr_src, csr_nrm, xwb,
                                                   deg, bg, h, hb);

    // ---- QKV (MT=64 -> 384 blocks; V cols written transposed into VT) ----
    mgemm_kernel<64, true, false, false><<<dim3(6, 64), 256, 0, stream>>>(
        hb, inwb, inb, nullptr, qkvb, VT,
        N_NODES, 768, DM_, DM_, DM_, 768, 0);

    // ---- flash attention (all-resident) + combine ----
    fattn_kernel<<<1024, 256, 0, stream>>>(qkvb, VT, Opart, ml);
    attn_combine_kernel<<<N_NODES, 256, 0, stream>>>(Opart, ml, attnb);

    // ---- out_proj (MT=64 non-split, plain f32 stores) + LN1 (zeroes tmp) ----
    mgemm_kernel<64, false, false, false><<<dim3(2, 64), 256, 0, stream>>>(
        attnb, owb, ob, tmp, nullptr, nullptr,
        N_NODES, DM_, DM_, DM_, DM_, DM_, 0);
    ln_kernel<<<N_NODES, 256, 0, stream>>>(h, tmp, g1, b1, h1, h1b, tmp);

    // ---- FFN ----
    mgemm_kernel<128, true, true, false><<<dim3(16, 32), 256, 0, stream>>>(
        h1b, l1wb, l1b, nullptr, ff1b, nullptr,
        N_NODES, DFF_, DM_, DM_, DM_, DFF_, 0);
    mgemm_kernel<64, false, false, true><<<dim3(2, 64, 2), 256, 0, stream>>>(
        ff1b, l2wb, l2b, tmp, nullptr, nullptr,
        N_NODES, DM_, DFF_, DFF_, DFF_, DM_, 1024);
    ln_kernel<<<N_NODES, 256, 0, stream>>>(h1, tmp, g2, b2, out, nullptr, nullptr);
}

// Round 17
// 168.863 us; speedup vs baseline: 1.1219x; 1.0295x over previous
//
#include <hip/hip_runtime.h>
#include <hip/hip_bf16.h>

#define N_NODES 4096
#define E_EDGES 131072
#define DIN_    512
#define DM_     256
#define DFF_    2048
#define EPS_    1e-5f
#define NSPLIT  8

typedef __attribute__((ext_vector_type(8))) short bf16x8;   // 8 bf16 = 4 VGPR
typedef __attribute__((ext_vector_type(4))) float f32x4;

__device__ __forceinline__ short f2b(float f) {
    union { float f; unsigned u; } x; x.f = f;
    unsigned r = x.u + 0x7fff + ((x.u >> 16) & 1);   // RNE
    return (short)(r >> 16);
}
__device__ __forceinline__ float b2f(short s) {
    union { int i; float f; } v; v.i = ((int)(unsigned short)s) << 16;
    return v.f;
}

// async global->LDS, 16B per lane; lptr must be wave-uniform (HW adds lane*16)
__device__ __forceinline__ void gload16(const void* g, void* l) {
    __builtin_amdgcn_global_load_lds(
        (const __attribute__((address_space(1))) void*)g,
        (__attribute__((address_space(3))) void*)l, 16, 0, 0);
}

// ---------------------------------------------------------------------------
// merged f32->bf16 casts + W_gcn transpose + deg/count zero, one launch.
// blocks [0,2048) x | [2048,2240) inw | [2240,2304) ow | [2304,2816) l1w
//        [2816,3328) l2w | [3328,3456) W_gcn transpose | 3456 zero deg/count
// ---------------------------------------------------------------------------
__global__ __launch_bounds__(256)
void castall_kernel(const float* __restrict__ x, short* __restrict__ xb,
                    const float* __restrict__ inw, short* __restrict__ inwb,
                    const float* __restrict__ ow, short* __restrict__ owb,
                    const float* __restrict__ l1w, short* __restrict__ l1wb,
                    const float* __restrict__ l2w, short* __restrict__ l2wb,
                    const float* __restrict__ Wg, short* __restrict__ WgT,
                    float* __restrict__ deg, int* __restrict__ count) {
    const int b = blockIdx.x;
    __shared__ float t[32][33];
    if (b == 3456) {                       // zero deg + count (replaces memset)
        #pragma unroll
        for (int i = 0; i < 16; ++i) {
            deg[threadIdx.x * 16 + i] = 0.f;
            count[threadIdx.x * 16 + i] = 0;
        }
        return;
    }
    if (b >= 3328) {                       // W_gcn [512][256] -> WgT [256][512]
        const int b2 = b - 3328;
        const int bk = (b2 & 15) * 32, bn = (b2 >> 4) * 32;
        const int tx = threadIdx.x & 31, ty = threadIdx.x >> 5;
        #pragma unroll
        for (int i = 0; i < 4; ++i) {
            int r = ty + i * 8;
            t[r][tx] = Wg[(size_t)(bk + r) * DM_ + bn + tx];
        }
        __syncthreads();
        #pragma unroll
        for (int i = 0; i < 4; ++i) {
            int r = ty + i * 8;
            WgT[(size_t)(bn + r) * DIN_ + bk + tx] = f2b(t[tx][r]);
        }
        return;
    }
    const float* s; short* d; int base;
    if (b < 2048)      { s = x;   d = xb;   base = b * 256; }
    else if (b < 2240) { s = inw; d = inwb; base = (b - 2048) * 256; }
    else if (b < 2304) { s = ow;  d = owb;  base = (b - 2240) * 256; }
    else if (b < 2816) { s = l1w; d = l1wb; base = (b - 2304) * 256; }
    else               { s = l2w; d = l2wb; base = (b - 2816) * 256; }
    const int i = base + threadIdx.x;
    float4 v = reinterpret_cast<const float4*>(s)[i];
    union { short s[4]; int2 v; } o;
    o.s[0] = f2b(v.x); o.s[1] = f2b(v.y); o.s[2] = f2b(v.z); o.s[3] = f2b(v.w);
    reinterpret_cast<int2*>(d)[i] = o.v;
}

// ---------------------------------------------------------------------------
// bf16 MFMA GEMM, 2-phase double-buffered, M-tile templated (MT = 128 or 64).
// (unchanged -- control)
// ---------------------------------------------------------------------------
template<int MT, bool BF16OUT, bool RELU, bool SPLITK>
__global__ __launch_bounds__(256)
void mgemm_kernel(const short* __restrict__ A, const short* __restrict__ B,
                  const float* __restrict__ bias,
                  float* __restrict__ Cf, short* __restrict__ Cb,
                  short* __restrict__ VTout,
                  int M, int N, int K, int lda, int ldb, int ldc, int kchunk)
{
    constexpr int MFN = MT / 32;                   // mf fragments per wave
    constexpr int ACH = MT / 64;                   // A-stage chunks per thread
    __shared__ __align__(16) short As[2][MT * 32];
    __shared__ __align__(16) short Bs[2][128 * 32];
    const int tid = threadIdx.x;
    const int lane = tid & 63, w = tid >> 6;
    const int c = lane & 15, g = lane >> 4;
    const int wm = (w >> 1) * (MT / 2), wn = (w & 1) * 64;
    const int bm = blockIdx.y * MT, bn = blockIdx.x * 128;
    int k0 = 0, kend = K;
    if (SPLITK) { k0 = blockIdx.z * kchunk; kend = min(K, k0 + kchunk); }

    const int wbase = (tid & ~63) * 16;            // wave-uniform LDS byte base
    int srowA[ACH], soffA[ACH];
    #pragma unroll
    for (int i = 0; i < ACH; ++i) {
        int L = i * 256 + tid;
        srowA[i] = L >> 2;
        soffA[i] = ((L & 3) ^ ((srowA[i] >> 1) & 3)) * 8;   // shorts
    }
    int srowB[2], soffB[2];
    #pragma unroll
    for (int i = 0; i < 2; ++i) {
        int L = i * 256 + tid;
        srowB[i] = L >> 2;
        soffB[i] = ((L & 3) ^ ((srowB[i] >> 1) & 3)) * 8;
    }

    auto stage = [&](int b, int kb) {
        #pragma unroll
        for (int i = 0; i < ACH; ++i)
            gload16(A + (size_t)(bm + srowA[i]) * lda + kb + soffA[i],
                    (char*)As[b] + i * 4096 + wbase);
        #pragma unroll
        for (int i = 0; i < 2; ++i)
            gload16(B + (size_t)(bn + srowB[i]) * ldb + kb + soffB[i],
                    (char*)Bs[b] + i * 4096 + wbase);
    };

    const int nsteps = (kend - k0) >> 5;
    f32x4 acc[MFN][4] = {};
    stage(0, k0);
    for (int s = 0; s < nsteps; ++s) {
        const int cur = s & 1;
        const bool pf = (s + 1 < nsteps);
        if (pf) stage(cur ^ 1, k0 + (s + 1) * 32);    // WAR-safe: drained at s-1 bar2
        if (pf) {
            if constexpr (ACH == 2) asm volatile("s_waitcnt vmcnt(4)" ::: "memory");
            else                    asm volatile("s_waitcnt vmcnt(3)" ::: "memory");
        } else {
            asm volatile("s_waitcnt vmcnt(0)" ::: "memory");
        }
        __builtin_amdgcn_s_barrier();                 // all waves' cur landed
        bf16x8 af[MFN], bf[4];
        #pragma unroll
        for (int mf = 0; mf < MFN; ++mf) {
            int r = wm + mf * 16 + c;
            int sw = (g ^ ((r >> 1) & 3)) * 16;
            af[mf] = *reinterpret_cast<const bf16x8*>((const char*)As[cur] + r * 64 + sw);
        }
        #pragma unroll
        for (int nf = 0; nf < 4; ++nf) {
            int r = wn + nf * 16 + c;
            int sw = (g ^ ((r >> 1) & 3)) * 16;
            bf[nf] = *reinterpret_cast<const bf16x8*>((const char*)Bs[cur] + r * 64 + sw);
        }
        #pragma unroll
        for (int mf = 0; mf < MFN; ++mf)
            #pragma unroll
            for (int nf = 0; nf < 4; ++nf)
                acc[mf][nf] = __builtin_amdgcn_mfma_f32_16x16x32_bf16(
                    af[mf], bf[nf], acc[mf][nf], 0, 0, 0);
        __builtin_amdgcn_s_barrier();                 // all reads of cur done
    }
    #pragma unroll
    for (int mf = 0; mf < MFN; ++mf) {
        const int row = bm + wm + mf * 16 + g * 4;
        #pragma unroll
        for (int nf = 0; nf < 4; ++nf) {
            const int col = bn + wn + nf * 16 + c;
            float bv = bias ? bias[col] : 0.f;
            #pragma unroll
            for (int v = 0; v < 4; ++v) {
                float val = acc[mf][nf][v];
                size_t o = (size_t)(row + v) * ldc + col;
                if (SPLITK) {
                    if (blockIdx.z == 0) val += bv;
                    atomicAdd(&Cf[o], val);
                } else {
                    val += bv;
                    if (RELU) val = fmaxf(val, 0.f);
                    if (BF16OUT) {
                        short bvs = f2b(val);
                        Cb[o] = bvs;
                        if (VTout && col >= 512)
                            VTout[(size_t)(col - 512) * N_NODES + row + v] = bvs;
                    } else {
                        Cf[o] = val;
                    }
                }
            }
        }
    }
}

// ---------------------------------------------------------------------------
// Flash attention (unchanged -- control).
// ---------------------------------------------------------------------------
__global__ __launch_bounds__(256)
void fattn_kernel(const short* __restrict__ qkv, const short* __restrict__ VT,
                  short* __restrict__ Opart, float* __restrict__ ml)
{
    const int bid = blockIdx.x;
    const int j = bid >> 3;
    const int pair = 2 * (bid & 7) + (j & 1);
    const int hd = pair >> 3, sp = pair & 7;
    const int qt = j >> 1;
    const int tid = threadIdx.x;
    const int w = tid >> 6, lane = tid & 63;
    const int c = lane & 15, g = lane >> 4;
    const int q0 = qt * 64 + w * 16;

    __shared__ __align__(16) char smem[40960];   // K 16K | V 16K | P 4x2048
    char* KldsB = smem;
    char* VldsB = smem + 16384;
    char* Pbase = smem + 32768 + w * 2048;       // [16][64] XOR-swizzled

    const char* qkvC = (const char*)qkv;
    const char* vtC  = (const char*)VT;
    const int wbase = (tid & ~63) * 16;          // wave-uniform LDS chunk base

    const short* Q = qkv + (size_t)q0 * 768 + hd * 128;
    bf16x8 qf[4];
    #pragma unroll
    for (int ks = 0; ks < 4; ++ks)
        qf[ks] = *reinterpret_cast<const bf16x8*>(Q + (size_t)c * 768 + ks * 32 + g * 8);

    auto stageK = [&](int kt) {
        const int key0 = kt * 64;
        #pragma unroll
        for (int i = 0; i < 4; ++i) {
            int Lr  = i * 4096 + tid * 16;
            int key = Lr >> 8;
            int lg  = (Lr & 255) ^ ((key & 7) << 4);
            const char* src = qkvC + ((size_t)(key0 + key) * 768 + 256 + hd * 128) * 2 + lg;
            gload16(src, KldsB + i * 4096 + wbase);
        }
    };
    auto stageV = [&](int kt) {
        const int key0 = kt * 64;
        #pragma unroll
        for (int i = 0; i < 4; ++i) {
            int Lr = i * 4096 + tid * 16;
            int dh = Lr >> 7;
            int lg = (Lr & 127) ^ ((dh & 7) << 4);
            const char* src = vtC + (size_t)(hd * 128 + dh) * 8192 + key0 * 2 + lg;
            gload16(src, VldsB + i * 4096 + wbase);
        }
    };

    f32x4 O[8] = {};
    float m[4]  = {-1e30f, -1e30f, -1e30f, -1e30f};
    float lsum[4] = {};                       // per-lane partial row sums
    const float C = 0.12751744f;              // log2(e)/sqrt(128)

    stageK(sp * 8);
    stageV(sp * 8);

    for (int t = 0; t < 8; ++t) {
        asm volatile("s_waitcnt vmcnt(4)" ::: "memory");
        __builtin_amdgcn_s_barrier();         // all waves' K(t) visible
        // ---- QK^T from LDS ----
        f32x4 S[4] = {};
        #pragma unroll
        for (int nf = 0; nf < 4; ++nf) {
            const int key = nf * 16 + c;
            const char* kr = KldsB + key * 256;
            const int sw = (key & 7) << 4;
            #pragma unroll
            for (int ks = 0; ks < 4; ++ks) {
                bf16x8 kf = *reinterpret_cast<const bf16x8*>(kr + ((ks * 64 + g * 16) ^ sw));
                S[nf] = __builtin_amdgcn_mfma_f32_16x16x32_bf16(qf[ks], kf, S[nf], 0, 0, 0);
            }
        }
        __builtin_amdgcn_s_barrier();         // all QK reads done -> K free
        if (t < 7) stageK(sp * 8 + t + 1);    // hides under softmax+PV

        // ---- online softmax, defer-max (log2 units, per-lane lsum) ----
        float z[4][4];
        float lmax[4];
        bool ok = true;
        #pragma unroll
        for (int v = 0; v < 4; ++v) {
            #pragma unroll
            for (int nf = 0; nf < 4; ++nf) z[nf][v] = S[nf][v] * C;
            lmax[v] = fmaxf(fmaxf(z[0][v], z[1][v]), fmaxf(z[2][v], z[3][v]));
            ok = ok && (lmax[v] <= m[v] + 8.f);
        }
        if (!__all(ok)) {                     // rare after tile 0
            float mx[4];
            #pragma unroll
            for (int v = 0; v < 4; ++v) mx[v] = lmax[v];
            #pragma unroll
            for (int off = 1; off <= 8; off <<= 1)
                #pragma unroll
                for (int v = 0; v < 4; ++v) mx[v] = fmaxf(mx[v], __shfl_xor(mx[v], off));
            #pragma unroll
            for (int v = 0; v < 4; ++v) {
                float mn = fmaxf(m[v], mx[v]);
                float scl = exp2f(m[v] - mn);
                m[v] = mn;
                lsum[v] *= scl;
                #pragma unroll
                for (int nf2 = 0; nf2 < 8; ++nf2) O[nf2][v] *= scl;
            }
        }
        #pragma unroll
        for (int nf = 0; nf < 4; ++nf)
            #pragma unroll
            for (int v = 0; v < 4; ++v) {
                float p = exp2f(z[nf][v] - m[v]);    // <= 256
                lsum[v] += p;
                union { float f; unsigned u; } pu; pu.f = p;
                const int row = 4 * g + v;
                const int bo = (row * 128 + (nf * 16 + c) * 2) ^ ((row & 7) << 4);
                *(short*)(Pbase + bo) = (short)(pu.u >> 16);   // RTZ
            }
        if (t < 7) asm volatile("s_waitcnt vmcnt(4)" ::: "memory");
        else       asm volatile("s_waitcnt vmcnt(0)" ::: "memory");
        __builtin_amdgcn_s_barrier();         // all waves' V(t) visible
        // ---- PV from LDS (own P region; same-wave ordering via lgkmcnt) ----
        bf16x8 pa[2];
        #pragma unroll
        for (int ks = 0; ks < 2; ++ks) {
            const int bo = (c * 128 + ks * 64 + g * 16) ^ ((c & 7) << 4);
            pa[ks] = *reinterpret_cast<const bf16x8*>(Pbase + bo);
        }
        #pragma unroll
        for (int nf2 = 0; nf2 < 8; ++nf2) {
            const int dh = nf2 * 16 + c;
            const char* vr = VldsB + dh * 128;
            const int sw = (dh & 7) << 4;
            #pragma unroll
            for (int ks = 0; ks < 2; ++ks) {
                bf16x8 vf = *reinterpret_cast<const bf16x8*>(vr + ((ks * 64 + g * 16) ^ sw));
                O[nf2] = __builtin_amdgcn_mfma_f32_16x16x32_bf16(pa[ks], vf, O[nf2], 0, 0, 0);
            }
        }
        __builtin_amdgcn_s_barrier();         // all PV reads done -> V free
        if (t < 7) stageV(sp * 8 + t + 1);    // hides under next QK+softmax
    }
    // epilogue: one cross-lane sum reduce for lsum
    #pragma unroll
    for (int off = 1; off <= 8; off <<= 1)
        #pragma unroll
        for (int v = 0; v < 4; ++v) lsum[v] += __shfl_xor(lsum[v], off);
    const size_t pbase = ((size_t)hd * NSPLIT + sp) * N_NODES;
    #pragma unroll
    for (int v = 0; v < 4; ++v) {
        const int row = q0 + 4 * g + v;
        const size_t rowo = (pbase + row) * 128;
        #pragma unroll
        for (int nf2 = 0; nf2 < 8; ++nf2)
            Opart[rowo + nf2 * 16 + c] = f2b(O[nf2][v]);
        if (c == 0) {
            ml[(pbase + row) * 2 + 0] = m[v];       // log2 units
            ml[(pbase + row) * 2 + 1] = lsum[v];
        }
    }
}

// combine NSPLIT partials -> attnb; grid 4096 x 256 thr (hd = tid>>7)
__global__ __launch_bounds__(256)
void attn_combine_kernel(const short* __restrict__ Opart, const float* __restrict__ ml,
                         short* __restrict__ attnb)
{
    const int row = blockIdx.x;
    const int hd = threadIdx.x >> 7, d = threadIdx.x & 127;
    float ms[NSPLIT], ls[NSPLIT];
    float mmax = -1e30f;
    #pragma unroll
    for (int s = 0; s < NSPLIT; ++s) {
        const size_t p = ((size_t)hd * NSPLIT + s) * N_NODES + row;
        ms[s] = ml[p * 2 + 0];
        ls[s] = ml[p * 2 + 1];
        mmax = fmaxf(mmax, ms[s]);
    }
    float lt = 0.f, acc = 0.f;
    #pragma unroll
    for (int s = 0; s < NSPLIT; ++s) {
        const float wgt = exp2f(ms[s] - mmax);
        lt += wgt * ls[s];
        const size_t p = ((size_t)hd * NSPLIT + s) * N_NODES + row;
        union { short s; unsigned short u; } b; b.s = Opart[p * 128 + d];
        union { unsigned u; float f; } cv; cv.u = ((unsigned)b.u) << 16;
        acc += wgt * cv.f;
    }
    attnb[(size_t)row * DM_ + hd * 128 + d] = f2b(acc / lt);
}

// ---------------------------------------------------------------------------
// GCN: degree accum (deg/count zeroed by castall), CSR build.
// ---------------------------------------------------------------------------
__global__ void deg_accum_kernel(const int* __restrict__ dst,
                                 const float* __restrict__ w,
                                 float* deg, int* count) {
    int e = blockIdx.x * 256 + threadIdx.x;
    if (e < E_EDGES) {
        int d = dst[e];
        atomicAdd(&deg[d], w[e]);
        atomicAdd(&count[d], 1);
    }
}
// scan of count -> start/cursor (1024 thr, 4 elems each); deg -> rsqrt(deg+1)
__global__ __launch_bounds__(1024)
void csr_scan_kernel(const int* __restrict__ count, int* __restrict__ start,
                     int* __restrict__ cursor, float* __restrict__ deg) {
    __shared__ int sum[1024];
    const int tid = threadIdx.x;
    const int base = tid * 4;
    #pragma unroll
    for (int i = 0; i < 4; ++i) {
        int n = base + i;
        deg[n] = rsqrtf(deg[n] + 1.0f);       // fold self-loop weight
    }
    int loc[4]; int s = 0;
    #pragma unroll
    for (int i = 0; i < 4; ++i) { loc[i] = count[base + i]; s += loc[i]; }
    sum[tid] = s;
    __syncthreads();
    for (int off = 1; off < 1024; off <<= 1) {
        int v = (tid >= off) ? sum[tid - off] : 0;
        __syncthreads();
        sum[tid] += v;
        __syncthreads();
    }
    int run = sum[tid] - s;
    #pragma unroll
    for (int i = 0; i < 4; ++i) {
        start[base + i] = run;
        cursor[base + i] = run;
        run += loc[i];
    }
    if (tid == 1023) start[N_NODES] = run;
}
__global__ void csr_fill_kernel(const int* __restrict__ src, const int* __restrict__ dst,
                                const float* __restrict__ w, const float* __restrict__ dinv,
                                int* __restrict__ cursor,
                                int* __restrict__ csr_src, float* __restrict__ csr_nrm) {
    int e = blockIdx.x * 256 + threadIdx.x;
    if (e >= E_EDGES) return;
    int s = src[e], d = dst[e];
    int pos = atomicAdd(&cursor[d], 1);
    csr_src[pos] = s;
    csr_nrm[pos] = dinv[s] * w[e] * dinv[d];
}
// wave-per-node gather: 1024 blocks x 4 waves; no LDS, no barriers.
// Lane owns 4 dims (int2 bf16 loads); neighbor loop unrolled x4 for MLP.
// Fuses self-loop + bias + ReLU; writes bf16 only.
__global__ __launch_bounds__(256)
void gcn_gather_kernel(const int* __restrict__ start, const int* __restrict__ csr_src,
                       const float* __restrict__ csr_nrm, const short* __restrict__ xwb,
                       const float* __restrict__ dinv, const float* __restrict__ b,
                       short* __restrict__ hb) {
    const int w = threadIdx.x >> 6, lane = threadIdx.x & 63;
    const int n = blockIdx.x * 4 + w;
    const int s0 = start[n], s1 = start[n + 1];
    const int col = lane * 4;
    float4 acc = {0.f, 0.f, 0.f, 0.f};
    int j = s0;
    for (; j + 4 <= s1; j += 4) {
        int   sj[4]; float wj[4]; int2 vj[4];
        #pragma unroll
        for (int u = 0; u < 4; ++u) { sj[u] = csr_src[j + u]; wj[u] = csr_nrm[j + u]; }
        #pragma unroll
        for (int u = 0; u < 4; ++u)
            vj[u] = *reinterpret_cast<const int2*>(xwb + (size_t)sj[u] * DM_ + col);
        #pragma unroll
        for (int u = 0; u < 4; ++u) {
            union { int i; float f; } e0, e1, e2, e3;
            e0.i = vj[u].x << 16; e1.i = vj[u].x & 0xffff0000;
            e2.i = vj[u].y << 16; e3.i = vj[u].y & 0xffff0000;
            acc.x = fmaf(wj[u], e0.f, acc.x);
            acc.y = fmaf(wj[u], e1.f, acc.y);
            acc.z = fmaf(wj[u], e2.f, acc.z);
            acc.w = fmaf(wj[u], e3.f, acc.w);
        }
    }
    for (; j < s1; ++j) {
        const int sj = csr_src[j];
        const float wj = csr_nrm[j];
        const int2 v = *reinterpret_cast<const int2*>(xwb + (size_t)sj * DM_ + col);
        union { int i; float f; } e0, e1, e2, e3;
        e0.i = v.x << 16; e1.i = v.x & 0xffff0000;
        e2.i = v.y << 16; e3.i = v.y & 0xffff0000;
        acc.x = fmaf(wj, e0.f, acc.x);
        acc.y = fmaf(wj, e1.f, acc.y);
        acc.z = fmaf(wj, e2.f, acc.z);
        acc.w = fmaf(wj, e3.f, acc.w);
    }
    const float di = dinv[n], d2 = di * di;
    const int2 pv = *reinterpret_cast<const int2*>(xwb + (size_t)n * DM_ + col);
    union { int i; float f; } x0, x1, x2, x3;
    x0.i = pv.x << 16; x1.i = pv.x & 0xffff0000;
    x2.i = pv.y << 16; x3.i = pv.y & 0xffff0000;
    const float4 bv = *reinterpret_cast<const float4*>(b + col);
    float v0 = fmaxf(acc.x + d2 * x0.f + bv.x, 0.f);
    float v1 = fmaxf(acc.y + d2 * x1.f + bv.y, 0.f);
    float v2 = fmaxf(acc.z + d2 * x2.f + bv.z, 0.f);
    float v3 = fmaxf(acc.w + d2 * x3.f + bv.w, 0.f);
    union { short s[4]; int2 v; } ob;
    ob.s[0] = f2b(v0); ob.s[1] = f2b(v1); ob.s[2] = f2b(v2); ob.s[3] = f2b(v3);
    *reinterpret_cast<int2*>(hb + (size_t)n * DM_ + col) = ob.v;
}

// ---------------------------------------------------------------------------
// LayerNorm(bf16 a + f32 b); writes f32 and/or bf16; optionally zeroes clearbuf.
// ---------------------------------------------------------------------------
__global__ __launch_bounds__(256)
void ln_kernel(const short* __restrict__ a, const float* __restrict__ b,
               const float* __restrict__ g, const float* __restrict__ be,
               float* __restrict__ outf, short* __restrict__ outb,
               float* __restrict__ clearbuf) {
    const int n = blockIdx.x, d = threadIdx.x;
    const size_t idx = (size_t)n * DM_ + d;
    float x = b2f(a[idx]) + b[idx];
    if (clearbuf) clearbuf[idx] = 0.f;
    float s = x;
    #pragma unroll
    for (int off = 32; off; off >>= 1) s += __shfl_xor(s, off);
    __shared__ float red[8];
    const int wid = d >> 6;
    if ((d & 63) == 0) red[wid] = s;
    __syncthreads();
    float mu = (red[0] + red[1] + red[2] + red[3]) * (1.f / 256.f);
    float c = x - mu;
    float q = c * c;
    #pragma unroll
    for (int off = 32; off; off >>= 1) q += __shfl_xor(q, off);
    if ((d & 63) == 0) red[4 + wid] = q;
    __syncthreads();
    float var = (red[4] + red[5] + red[6] + red[7]) * (1.f / 256.f);
    float v = c * rsqrtf(var + EPS_) * g[d] + be[d];
    if (outf) outf[idx] = v;
    if (outb) outb[idx] = f2b(v);
}

// ---------------------------------------------------------------------------
extern "C" void kernel_launch(void* const* d_in, const int* in_sizes, int n_in,
                              void* d_out, int out_size, void* d_ws, size_t ws_size,
                              hipStream_t stream) {
    const float* x   = (const float*)d_in[0];
    const int*   ei  = (const int*)  d_in[1];
    const float* ew  = (const float*)d_in[2];
    const float* Wg  = (const float*)d_in[3];
    const float* bg  = (const float*)d_in[4];
    const float* inw = (const float*)d_in[5];
    const float* inb = (const float*)d_in[6];
    const float* ow  = (const float*)d_in[7];
    const float* ob  = (const float*)d_in[8];
    const float* l1w = (const float*)d_in[9];
    const float* l1b = (const float*)d_in[10];
    const float* l2w = (const float*)d_in[11];
    const float* l2b = (const float*)d_in[12];
    const float* g1  = (const float*)d_in[13];
    const float* b1  = (const float*)d_in[14];
    const float* g2  = (const float*)d_in[15];
    const float* b2  = (const float*)d_in[16];
    float* out = (float*)d_out;

    char* ws = (char*)d_ws;
    size_t off = 0;
    auto alloc = [&](size_t bytes) {
        void* p = ws + off;
        off += (bytes + 255) & ~(size_t)255;
        return p;
    };
    float* deg     = (float*)alloc((size_t)N_NODES * 4);
    int*   count   = (int*)  alloc((size_t)N_NODES * 4);
    float* tmp     = (float*)alloc((size_t)N_NODES * DM_ * 4);         // 4 MB
    int*   startA  = (int*)  alloc((size_t)(N_NODES + 1) * 4);
    int*   cursor  = (int*)  alloc((size_t)N_NODES * 4);
    int*   csr_src = (int*)  alloc((size_t)E_EDGES * 4);
    float* csr_nrm = (float*)alloc((size_t)E_EDGES * 4);
    short* xb    = (short*)alloc((size_t)N_NODES * DIN_ * 2);          // 4 MB
    short* WgT   = (short*)alloc((size_t)DM_ * DIN_ * 2);
    short* inwb  = (short*)alloc((size_t)768 * DM_ * 2);
    short* owb   = (short*)alloc((size_t)DM_ * DM_ * 2);
    short* l1wb  = (short*)alloc((size_t)DFF_ * DM_ * 2);
    short* l2wb  = (short*)alloc((size_t)DM_ * DFF_ * 2);
    short* xwb   = (short*)alloc((size_t)N_NODES * DM_ * 2);           // 2 MB
    short* hb    = (short*)alloc((size_t)N_NODES * DM_ * 2);
    short* qkvb  = (short*)alloc((size_t)N_NODES * 768 * 2);           // 6 MB
    short* VT    = (short*)alloc((size_t)DM_ * N_NODES * 2);           // 2 MB
    short* attnb = (short*)alloc((size_t)N_NODES * DM_ * 2);
    short* h1b   = (short*)alloc((size_t)N_NODES * DM_ * 2);
    size_t opart_b = (size_t)2 * NSPLIT * N_NODES * 128 * 2;           // 16.8 MB
    size_t ml_b    = (size_t)2 * NSPLIT * N_NODES * 2 * 4;             // 0.5 MB
    size_t ff1_b   = (size_t)N_NODES * DFF_ * 2;                       // 16 MB
    char*  R     = (char*)alloc(opart_b + ml_b > ff1_b ? opart_b + ml_b : ff1_b);
    short* Opart = (short*)R;
    float* ml    = (float*)(R + opart_b);
    short* ff1b  = (short*)R;
    (void)ws_size; (void)in_sizes; (void)n_in; (void)out_size;

    const int* srcI = ei;
    const int* dstI = ei + E_EDGES;

    // ---- merged casts + W_gcn transpose + deg/count zero (one launch) ----
    castall_kernel<<<3457, 256, 0, stream>>>(x, xb, inw, inwb, ow, owb,
                                             l1w, l1wb, l2w, l2wb, Wg, WgT,
                                             deg, count);

    // ---- GCN ----
    deg_accum_kernel<<<E_EDGES / 256, 256, 0, stream>>>(dstI, ew, deg, count);
    csr_scan_kernel<<<1, 1024, 0, stream>>>(count, startA, cursor, deg);
    csr_fill_kernel<<<E_EDGES / 256, 256, 0, stream>>>(srcI, dstI, ew, deg, cursor,
                                                       csr_src, csr_nrm);
    // xw: MT=64 non-split, bf16 out directly
    mgemm_kernel<64, true, false, false><<<dim3(2, 64), 256, 0, stream>>>(
        xb, WgT, nullptr, nullptr, xwb, nullptr,
        N_NODES, DM_, DIN_, DIN_, DIN_, DM_, 0);
    gcn_gather_kernel<<<1024, 256, 0, stream>>>(startA, csr_src, csr_nrm, xwb,
                                                deg, bg, hb);

    // ---- QKV (MT=64 -> 384 blocks; V cols written transposed into VT) ----
    mgemm_kernel<64, true, false, false><<<dim3(6, 64), 256, 0, stream>>>(
        hb, inwb, inb, nullptr, qkvb, VT,
        N_NODES, 768, DM_, DM_, DM_, 768, 0);

    // ---- flash attention (all-resident) + combine ----
    fattn_kernel<<<1024, 256, 0, stream>>>(qkvb, VT, Opart, ml);
    attn_combine_kernel<<<N_NODES, 256, 0, stream>>>(Opart, ml, attnb);

    // ---- out_proj (MT=64 non-split, plain f32 stores) + LN1 (zeroes tmp) ----
    mgemm_kernel<64, false, false, false><<<dim3(2, 64), 256, 0, stream>>>(
        attnb, owb, ob, tmp, nullptr, nullptr,
        N_NODES, DM_, DM_, DM_, DM_, DM_, 0);
    ln_kernel<<<N_NODES, 256, 0, stream>>>(hb, tmp, g1, b1, nullptr, h1b, tmp);

    // ---- FFN ----
    mgemm_kernel<128, true, true, false><<<dim3(16, 32), 256, 0, stream>>>(
        h1b, l1wb, l1b, nullptr, ff1b, nullptr,
        N_NODES, DFF_, DM_, DM_, DM_, DFF_, 0);
    mgemm_kernel<64, false, false, true><<<dim3(2, 64, 2), 256, 0, stream>>>(
        ff1b, l2wb, l2b, tmp, nullptr, nullptr,
        N_NODES, DM_, DFF_, DFF_, DFF_, DM_, 1024);
    ln_kernel<<<N_NODES, 256, 0, stream>>>(h1b, tmp, g2, b2, out, nullptr, nullptr);
}